// Round 6
// baseline (685.365 us; speedup 1.0000x reference)
//
#include <hip/hip_runtime.h>

static constexpr int N_NODES = 100000;
static constexpr int N_EDGES = 3200000;
static constexpr int NC16    = N_NODES * 16;         // 1.6M
static constexpr int RB      = 64;                   // nodes per bucket
static constexpr int NB      = (N_NODES + RB - 1) / RB;   // 1563 buckets
static constexpr int CAP     = 2560;                 // per-bucket cap (mean 2047, +11 sigma)
static constexpr int NPB     = 512;                  // partition blocks
static constexpr int EPB     = N_EDGES / NPB;        // 6250 edges/partition block

// ---------- small float4 helpers ----------
__device__ __forceinline__ float4 v4fma(float s, float4 w, float4 acc) {
    acc.x = fmaf(s, w.x, acc.x);
    acc.y = fmaf(s, w.y, acc.y);
    acc.z = fmaf(s, w.z, acc.z);
    acc.w = fmaf(s, w.w, acc.w);
    return acc;
}

// broadcast all 4 components from quad-lane KK (v_mov_b32 dpp quad_perm — VALU pipe)
template<int KK>
__device__ __forceinline__ float4 qbcast(float4 a) {
    constexpr int ctrl = KK * 0x55;   // quad_perm:[KK,KK,KK,KK]
    float4 r;
    r.x = __int_as_float(__builtin_amdgcn_mov_dpp(__float_as_int(a.x), ctrl, 0xF, 0xF, true));
    r.y = __int_as_float(__builtin_amdgcn_mov_dpp(__float_as_int(a.y), ctrl, 0xF, 0xF, true));
    r.z = __int_as_float(__builtin_amdgcn_mov_dpp(__float_as_int(a.z), ctrl, 0xF, 0xF, true));
    r.w = __int_as_float(__builtin_amdgcn_mov_dpp(__float_as_int(a.w), ctrl, 0xF, 0xF, true));
    return r;
}

// ew(channels of this lane) += sum over k in [4*KK, 4*KK+4) of a[k] * Wcol[k]
template<int KK>
__device__ __forceinline__ float4 ewstep(float4 a, const float4* wc, float4 ew) {
    float4 v = qbcast<KK>(a);
    ew = v4fma(v.x, wc[4*KK + 0], ew);
    ew = v4fma(v.y, wc[4*KK + 1], ew);
    ew = v4fma(v.z, wc[4*KK + 2], ew);
    ew = v4fma(v.w, wc[4*KK + 3], ew);
    return ew;
}

// Swizzled fp64 LDS accumulate (verified r2-r5): channel c of node dl lives at
// word dl*16 + ((c + dl) & 15) -> lanes spread over all 16 bank-pairs.
__device__ __forceinline__ void accum4(double* __restrict__ accS, int dl, int c4,
                                       double v0, double v1, double v2, double v3) {
    double* row = accS + dl * 16;
    const int pb = (c4 * 4 + dl) & 15;
    atomicAdd(row + ((pb + 0) & 15), v0);
    atomicAdd(row + ((pb + 1) & 15), v1);
    atomicAdd(row + ((pb + 2) & 15), v2);
    atomicAdd(row + ((pb + 3) & 15), v3);
}

// ---------------- zero gcount (kernel, NOT hipMemsetAsync — graph-capture-proof) ----
__global__ __launch_bounds__(256)
void k_zero(int* g) {
    int t = blockIdx.x * 256 + threadIdx.x;
    if (t < NB) g[t] = 0;
}

// ================= partition: meta-only (8B/edge scatter; r4-proven) =========
__global__ __launch_bounds__(1024)
void k_part(const int* __restrict__ srcI, const int* __restrict__ dstI,
            int* __restrict__ gcount, int2* __restrict__ meta)
{
    __shared__ int hist[NB];                  // 6.25 KB
    const int tid = threadIdx.x;
    const int e0  = blockIdx.x * EPB;
    for (int t = tid; t < NB; t += 1024) hist[t] = 0;
    __syncthreads();
    for (int i = tid; i < EPB; i += 1024) {
        int d = dstI[e0 + i];
        atomicAdd(&hist[d >> 6], 1);          // LDS int atomic (exact, commutative)
    }
    __syncthreads();
    for (int t = tid; t < NB; t += 1024) {
        int h = hist[t];
        hist[t] = (h > 0) ? atomicAdd(&gcount[t], h) : 0;   // one global atomic/bucket
    }
    __syncthreads();
    for (int i = tid; i < EPB; i += 1024) {
        int e = e0 + i;
        int d = dstI[e];
        int s = srcI[e];
        int b = d >> 6;
        int pos = atomicAdd(&hist[b], 1);     // LDS cursor
        if (pos < CAP)                        // OOB insurance (never expected)
            meta[b * CAP + pos] = make_int2(e, (s << 6) | (d & 63));
    }
}

// ================= deg pass + fused dinv + fused p1 = dinv*(x@W1) ============
// Main loop identical to r4's proven k_bucket<0>; epilogue additionally does
// the whole k_xw1 for this block's 64 nodes (W1 staged in LDS).
__global__ __launch_bounds__(512)
void k_deg(const float* __restrict__ ea, const int2* __restrict__ meta,
           const int* __restrict__ gcount, const float* __restrict__ We,
           const float* __restrict__ be,
           const float* __restrict__ x, const float* __restrict__ W1,
           float* __restrict__ dinv, float* __restrict__ pA)
{
    __shared__ double accS[RB * 16];              // 8 KB
    __shared__ float4 w1s[512];                   // 8 KB  [k][c4], k=0..127
    const int tid = threadIdx.x;
    const int b   = blockIdx.x;
    for (int t = tid; t < RB * 16; t += 512) accS[t] = 0.0;
    w1s[tid] = ((const float4*)W1)[tid];          // 512 float4 = full W1

    const int c4 = tid & 3;
    float4 wc[16];
    const float4* We4 = (const float4*)We;
#pragma unroll
    for (int k = 0; k < 16; ++k) wc[k] = We4[k * 4 + c4];
    const float4 bev = ((const float4*)be)[c4];
    const int cnt = min(gcount[b], CAP);
    const int2* ml = meta + b * CAP;
    const float4* ea4 = (const float4*)ea;
    __syncthreads();

#pragma unroll 2
    for (int i = tid >> 2; i < cnt; i += 128) {
        int2 m = ml[i];                           // quad shares 8B -> broadcast
        float4 a = ea4[m.x * 4 + c4];             // random 64B granule (natural order, L3-friendly)
        const int dl = m.y & 63;
        float4 ew = bev;
        ew = ewstep<0>(a, wc, ew);
        ew = ewstep<1>(a, wc, ew);
        ew = ewstep<2>(a, wc, ew);
        ew = ewstep<3>(a, wc, ew);
        accum4(accS, dl, c4, (double)ew.x, (double)ew.y, (double)ew.z, (double)ew.w);
    }
    __syncthreads();

    // epilogue (256 active threads; full quads): dinv then p1 = dinv*(x@W1)
    if (tid < RB * 4) {
        const int nl = tid >> 2;
        const int ng = b * RB + nl;
        if (ng < N_NODES) {
            const double* s = accS + nl * 16;
            const int pb = (c4 * 4 + nl) & 15;
            float4 dv;
            float d0 = (float)s[(pb + 0) & 15] + 1.0f; dv.x = (d0 > 0.f) ? rsqrtf(d0 + 1e-12f) : 0.f;
            float d1 = (float)s[(pb + 1) & 15] + 1.0f; dv.y = (d1 > 0.f) ? rsqrtf(d1 + 1e-12f) : 0.f;
            float d2 = (float)s[(pb + 2) & 15] + 1.0f; dv.z = (d2 > 0.f) ? rsqrtf(d2 + 1e-12f) : 0.f;
            float d3 = (float)s[(pb + 3) & 15] + 1.0f; dv.w = (d3 > 0.f) ? rsqrtf(d3 + 1e-12f) : 0.f;
            ((float4*)dinv)[ng * 4 + c4] = dv;

            // x @ W1 for this node (quad lanes broadcast-load the x row)
            const float4* x4 = (const float4*)x;
            float4 acc = make_float4(0.f, 0.f, 0.f, 0.f);
            for (int k4 = 0; k4 < 32; ++k4) {
                float4 xv = x4[ng * 32 + k4];
                acc = v4fma(xv.x, w1s[(k4 * 4 + 0) * 4 + c4], acc);
                acc = v4fma(xv.y, w1s[(k4 * 4 + 1) * 4 + c4], acc);
                acc = v4fma(xv.z, w1s[(k4 * 4 + 2) * 4 + c4], acc);
                acc = v4fma(xv.w, w1s[(k4 * 4 + 3) * 4 + c4], acc);
            }
            float4 o;
            o.x = dv.x * acc.x; o.y = dv.y * acc.y;
            o.z = dv.z * acc.z; o.w = dv.w * acc.w;
            ((float4*)pA)[ng * 4 + c4] = o;
        }
    }
}

// ================= gather pass + fused node epilogue ========================
// FIN==0 (gather1+mid): pout = dinv * ((relu(dinv*(agg+pin)+b1)) @ W2)
// FIN==1 (gather2+out): pout = dinv * (agg+pin) + b2
// pin/pout are distinct buffers -> no in-place race with the gather reads.
template<int FIN>
__global__ __launch_bounds__(512)
void k_gather(const float* __restrict__ ea, const int2* __restrict__ meta,
              const int* __restrict__ gcount, const float* __restrict__ We,
              const float* __restrict__ be, const float* __restrict__ dinv,
              const float* __restrict__ pin, const float* __restrict__ Wb,  // W2 or b2
              const float* __restrict__ b1, float* __restrict__ pout)
{
    __shared__ double accS[RB * 16];              // 8 KB
    const int tid = threadIdx.x;
    const int b   = blockIdx.x;
    for (int t = tid; t < RB * 16; t += 512) accS[t] = 0.0;

    const int c4 = tid & 3;
    float4 wc[16];
    const float4* We4 = (const float4*)We;
#pragma unroll
    for (int k = 0; k < 16; ++k) wc[k] = We4[k * 4 + c4];
    const float4 bev = ((const float4*)be)[c4];
    const int cnt = min(gcount[b], CAP);
    const int2* ml = meta + b * CAP;
    const float4* ea4 = (const float4*)ea;
    const float4* p4  = (const float4*)pin;
    __syncthreads();

#pragma unroll 2
    for (int i = tid >> 2; i < cnt; i += 128) {
        int2 m = ml[i];
        float4 a = ea4[m.x * 4 + c4];             // random 64B granule
        float4 pv = p4[((unsigned)m.y >> 6) * 4 + c4];  // pin = 6.4MB, L2/L3-hot
        const int dl = m.y & 63;
        float4 ew = bev;
        ew = ewstep<0>(a, wc, ew);
        ew = ewstep<1>(a, wc, ew);
        ew = ewstep<2>(a, wc, ew);
        ew = ewstep<3>(a, wc, ew);
        accum4(accS, dl, c4,
               (double)(ew.x * pv.x), (double)(ew.y * pv.y),
               (double)(ew.z * pv.z), (double)(ew.w * pv.w));
    }
    __syncthreads();

    // epilogue (256 active threads; full quads)
    if (tid < RB * 4) {
        const int nl = tid >> 2;
        const int ng = b * RB + nl;
        if (ng < N_NODES) {
            const double* s = accS + nl * 16;
            const int pb = (c4 * 4 + nl) & 15;
            float4 av;
            av.x = (float)s[(pb + 0) & 15];
            av.y = (float)s[(pb + 1) & 15];
            av.z = (float)s[(pb + 2) & 15];
            av.w = (float)s[(pb + 3) & 15];
            const float4 pv = ((const float4*)pin)[ng * 4 + c4];
            const float4 dv = ((const float4*)dinv)[ng * 4 + c4];
            float4 o;
            if (FIN == 0) {
                // k_mid: h1 = relu(dv*(av+pv)+b1); h2 = h1@W2; pout = dv*h2
                const float4 b1v = ((const float4*)b1)[c4];
                float4 h1;
                h1.x = fmaxf(fmaf(dv.x, av.x + pv.x, b1v.x), 0.f);
                h1.y = fmaxf(fmaf(dv.y, av.y + pv.y, b1v.y), 0.f);
                h1.z = fmaxf(fmaf(dv.z, av.z + pv.z, b1v.z), 0.f);
                h1.w = fmaxf(fmaf(dv.w, av.w + pv.w, b1v.w), 0.f);
                float4 wc2[16];
                const float4* W24 = (const float4*)Wb;
#pragma unroll
                for (int k = 0; k < 16; ++k) wc2[k] = W24[k * 4 + c4];
                float4 h2 = make_float4(0.f, 0.f, 0.f, 0.f);
                h2 = ewstep<0>(h1, wc2, h2);
                h2 = ewstep<1>(h1, wc2, h2);
                h2 = ewstep<2>(h1, wc2, h2);
                h2 = ewstep<3>(h1, wc2, h2);
                o.x = dv.x * h2.x; o.y = dv.y * h2.y;
                o.z = dv.z * h2.z; o.w = dv.w * h2.w;
            } else {
                // k_out: out = dv*(av+pv) + b2
                const float4 b2v = ((const float4*)Wb)[c4];
                o.x = fmaf(dv.x, av.x + pv.x, b2v.x);
                o.y = fmaf(dv.y, av.y + pv.y, b2v.y);
                o.z = fmaf(dv.z, av.z + pv.z, b2v.z);
                o.w = fmaf(dv.w, av.w + pv.w, b2v.w);
            }
            ((float4*)pout)[ng * 4 + c4] = o;
        }
    }
}

extern "C" void kernel_launch(void* const* d_in, const int* in_sizes, int n_in,
                              void* d_out, int out_size, void* d_ws, size_t ws_size,
                              hipStream_t stream)
{
    const float* x   = (const float*)d_in[0];
    const int*   ei  = (const int*)d_in[1];
    const float* ea  = (const float*)d_in[2];
    const float* We  = (const float*)d_in[3];
    const float* be  = (const float*)d_in[4];
    const float* W1  = (const float*)d_in[5];
    const float* b1  = (const float*)d_in[6];
    const float* W2  = (const float*)d_in[7];
    const float* b2  = (const float*)d_in[8];
    float* out = (float*)d_out;

    const int* srcI = ei;
    const int* dstI = ei + N_EDGES;

    // workspace carve (~51.3 MB; ws proven >=281 MB in r2/r3/r5)
    float* dinv = (float*)d_ws;          //                             (6.4 MB)
    float* pA   = dinv + NC16;           // p1                          (6.4 MB)
    float* pB   = pA + NC16;             // p2 (separate: no race)      (6.4 MB)
    int2*  meta = (int2*)(pB + NC16);    // NB*CAP*8B                   (32.0 MB)
    int*   gcount = (int*)(meta + (size_t)NB * CAP);  // NB ints

    hipLaunchKernelGGL(k_zero, dim3((NB + 255) / 256), dim3(256), 0, stream, gcount);
    hipLaunchKernelGGL(k_part, dim3(NPB), dim3(1024), 0, stream,
                       srcI, dstI, gcount, meta);
    hipLaunchKernelGGL(k_deg, dim3(NB), dim3(512), 0, stream,
                       ea, meta, gcount, We, be, x, W1, dinv, pA);
    hipLaunchKernelGGL((k_gather<0>), dim3(NB), dim3(512), 0, stream,
                       ea, meta, gcount, We, be, dinv, pA, W2, b1, pB);
    hipLaunchKernelGGL((k_gather<1>), dim3(NB), dim3(512), 0, stream,
                       ea, meta, gcount, We, be, dinv, pB, b2, (const float*)nullptr, out);
}